// Round 2
// baseline (5072.942 us; speedup 1.0000x reference)
//
#include <hip/hip_runtime.h>

typedef __attribute__((ext_vector_type(8))) short s16x8;

#define EPSF 1e-36f

static __device__ __forceinline__ float bf2f(short s) {
  return __builtin_bit_cast(float, ((unsigned)(unsigned short)s) << 16);
}

static __device__ __forceinline__ short f2bf(float f) {
  unsigned u = __builtin_bit_cast(unsigned, f);
  u = (u + 0x7FFFu + ((u >> 16) & 1u)) >> 16;
  return (short)u;
}

// ---------------- prep: embedding table Em[site][n][16] (f32) ----------------
extern "C" __global__ void prep_emb_k(const float* __restrict__ x, float* __restrict__ Em) {
  int id = blockIdx.x * 256 + threadIdx.x;   // 128 sites * 1024 samples
  int site = id >> 10, n = id & 1023;
  float x0 = x[(n * 128 + site) * 2 + 0];
  float x1 = x[(n * 128 + site) * 2 + 1];
  const float P5 = 1.57079632679f, P25 = 0.785398163397f, R = 0.70710678118f;
  float u[4] = {sinf(P5 * x0) * R, cosf(P5 * x0) * R, sinf(P25 * x0) * R, cosf(P25 * x0) * R};
  float v[4] = {sinf(P5 * x1) * R, cosf(P5 * x1) * R, sinf(P25 * x1) * R, cosf(P25 * x1) * R};
#pragma unroll
  for (int a = 0; a < 4; ++a) {
    float4 o;
    o.x = u[a] * v[0]; o.y = u[a] * v[1]; o.z = u[a] * v[2]; o.w = u[a] * v[3];
    *(float4*)&Em[id * 16 + a * 4] = o;
  }
}

// ---------------- prep: weights -> bf16, layout As[site][m][l][e][r] ----------------
extern "C" __global__ void prep_w_k(const float* __restrict__ wb, const float* __restrict__ wsm,
                                    short* __restrict__ As) {
  int site = blockIdx.x;
  bool big = (site & 7) == 0;
  int nE = big ? 262144 : 16384;
  int nb = (site + 7) >> 3;                       // #big sites before 'site'
  int bs = nb * 262144 + (site - nb) * 16384;     // flat offset of this site's slices
  int kb = site >> 3;
  int ksm = site - kb - 1;
  for (int i = threadIdx.x; i < nE; i += 256) {
    int r = i & 31, e = (i >> 5) & 15, l = (i >> 9) & 31, m = i >> 14;
    float val = big ? wb[(((kb * 32 + l) * 16 + e) * 16 + m) * 32 + r]
                    : wsm[((ksm * 32 + l) * 16 + e) * 32 + r];
    if (site == 0 && l != 0) val = 0.f;
    if (site == 127 && r != 0) val = 0.f;
    As[bs + i] = f2bf(val);
  }
}

// ---------------- sample chains: 256 blocks x 256 thr, wave = sample ----------------
extern "C" __global__ void __launch_bounds__(256, 1)
tn_samples(const short* __restrict__ As, const float* __restrict__ Em, float* __restrict__ out) {
  __shared__ __align__(16) short Ast[32 * 520];      // A slice [l][e*32+r], row pad->520
  __shared__ __align__(16) float Bb[4][32 * 36];     // per-wave B[l][r], pad 36
  __shared__ __align__(16) float Cb[4][32 * 36];     // per-wave C[i][j], pad 36

  const int tid = threadIdx.x;
  const int lane = tid & 63;
  const int w = tid >> 6;
  const int i = lane & 31;          // row owned by this lane
  const int hi = lane >> 5;         // column half
  const int n = blockIdx.x * 4 + w; // sample
  float* Bw = Bb[w];
  float* Cw = Cb[w];

  float Tall[32];                   // full row i of T
  float log_norm = 0.f;
#pragma unroll
  for (int k = 0; k < 32; ++k) Tall[k] = 0.f;
  if (i == 0) Tall[0] = 1.f;        // T_init = e0 e0^T

  int bs = 0;
#pragma unroll 1
  for (int site = 0; site < 128; ++site) {
    const int nm = ((site & 7) == 0) ? 16 : 1;
    // embedding coefficients for (site, n)
    float er[16];
    {
      const float4* ep = (const float4*)&Em[(site * 1024 + n) * 16];
      float4 q0 = ep[0], q1 = ep[1], q2 = ep[2], q3 = ep[3];
      er[0] = q0.x; er[1] = q0.y; er[2] = q0.z; er[3] = q0.w;
      er[4] = q1.x; er[5] = q1.y; er[6] = q1.z; er[7] = q1.w;
      er[8] = q2.x; er[9] = q2.y; er[10] = q2.z; er[11] = q2.w;
      er[12] = q3.x; er[13] = q3.y; er[14] = q3.z; er[15] = q3.w;
    }
    float Tacc[16];
#pragma unroll
    for (int c = 0; c < 16; ++c) Tacc[c] = 0.f;

#pragma unroll 1
    for (int m = 0; m < nm; ++m) {
      // ---- stage A slice (site,m): 16384 shorts, cooperative ----
      __syncthreads();
      {
        const short* src = &As[bs + m * 16384 + tid * 64];
        short* dst = &Ast[(tid >> 3) * 520 + (tid & 7) * 64];
#pragma unroll
        for (int j = 0; j < 8; ++j)
          *(s16x8*)(dst + 8 * j) = *(const s16x8*)(src + 8 * j);
      }
      __syncthreads();

      // ---- B-form: B[l][r] = sum_e er[e] * A[l][e][r]; lane owns l=i, r=16*hi+c ----
      {
        float acc[16];
#pragma unroll
        for (int c = 0; c < 16; ++c) acc[c] = 0.f;
#pragma unroll
        for (int e = 0; e < 16; ++e) {
          const s16x8 a0 = *(const s16x8*)&Ast[i * 520 + e * 32 + 16 * hi];
          const s16x8 a1 = *(const s16x8*)&Ast[i * 520 + e * 32 + 16 * hi + 8];
          const float ce = er[e];
#pragma unroll
          for (int c = 0; c < 8; ++c) {
            acc[c] = fmaf(ce, bf2f(a0[c]), acc[c]);
            acc[8 + c] = fmaf(ce, bf2f(a1[c]), acc[8 + c]);
          }
        }
#pragma unroll
        for (int q = 0; q < 4; ++q) {
          float4 o; o.x = acc[4 * q]; o.y = acc[4 * q + 1]; o.z = acc[4 * q + 2]; o.w = acc[4 * q + 3];
          *(float4*)&Bw[i * 36 + 16 * hi + 4 * q] = o;
        }
      }
      // (wave-private LDS: no barrier needed)

      // ---- GEMM1: C[i][j] = sum_k T[i][k] B[k][j] ----
      {
        float acc[16];
#pragma unroll
        for (int c = 0; c < 16; ++c) acc[c] = 0.f;
#pragma unroll
        for (int k = 0; k < 32; ++k) {
          const float tk = Tall[k];
          const float4 b0 = *(const float4*)&Bw[k * 36 + 16 * hi];
          const float4 b1 = *(const float4*)&Bw[k * 36 + 16 * hi + 4];
          const float4 b2 = *(const float4*)&Bw[k * 36 + 16 * hi + 8];
          const float4 b3 = *(const float4*)&Bw[k * 36 + 16 * hi + 12];
          acc[0] = fmaf(tk, b0.x, acc[0]);  acc[1] = fmaf(tk, b0.y, acc[1]);
          acc[2] = fmaf(tk, b0.z, acc[2]);  acc[3] = fmaf(tk, b0.w, acc[3]);
          acc[4] = fmaf(tk, b1.x, acc[4]);  acc[5] = fmaf(tk, b1.y, acc[5]);
          acc[6] = fmaf(tk, b1.z, acc[6]);  acc[7] = fmaf(tk, b1.w, acc[7]);
          acc[8] = fmaf(tk, b2.x, acc[8]);  acc[9] = fmaf(tk, b2.y, acc[9]);
          acc[10] = fmaf(tk, b2.z, acc[10]); acc[11] = fmaf(tk, b2.w, acc[11]);
          acc[12] = fmaf(tk, b3.x, acc[12]); acc[13] = fmaf(tk, b3.y, acc[13]);
          acc[14] = fmaf(tk, b3.z, acc[14]); acc[15] = fmaf(tk, b3.w, acc[15]);
        }
#pragma unroll
        for (int q = 0; q < 4; ++q) {
          float4 o; o.x = acc[4 * q]; o.y = acc[4 * q + 1]; o.z = acc[4 * q + 2]; o.w = acc[4 * q + 3];
          *(float4*)&Cw[i * 36 + 16 * hi + 4 * q] = o;
        }
      }

      // ---- GEMM2: Tacc[i][j] += sum_k B[k][i] * C[k][j] ----
      {
#pragma unroll
        for (int k = 0; k < 32; ++k) {
          const float bk = Bw[k * 36 + i];
          const float4 c0 = *(const float4*)&Cw[k * 36 + 16 * hi];
          const float4 c1 = *(const float4*)&Cw[k * 36 + 16 * hi + 4];
          const float4 c2 = *(const float4*)&Cw[k * 36 + 16 * hi + 8];
          const float4 c3 = *(const float4*)&Cw[k * 36 + 16 * hi + 12];
          Tacc[0] = fmaf(bk, c0.x, Tacc[0]);  Tacc[1] = fmaf(bk, c0.y, Tacc[1]);
          Tacc[2] = fmaf(bk, c0.z, Tacc[2]);  Tacc[3] = fmaf(bk, c0.w, Tacc[3]);
          Tacc[4] = fmaf(bk, c1.x, Tacc[4]);  Tacc[5] = fmaf(bk, c1.y, Tacc[5]);
          Tacc[6] = fmaf(bk, c1.z, Tacc[6]);  Tacc[7] = fmaf(bk, c1.w, Tacc[7]);
          Tacc[8] = fmaf(bk, c2.x, Tacc[8]);  Tacc[9] = fmaf(bk, c2.y, Tacc[9]);
          Tacc[10] = fmaf(bk, c2.z, Tacc[10]); Tacc[11] = fmaf(bk, c2.w, Tacc[11]);
          Tacc[12] = fmaf(bk, c3.x, Tacc[12]); Tacc[13] = fmaf(bk, c3.y, Tacc[13]);
          Tacc[14] = fmaf(bk, c3.z, Tacc[14]); Tacc[15] = fmaf(bk, c3.w, Tacc[15]);
        }
      }
    }

    // ---- site end: rescale into Tall, or final logit ----
    if (site < 127) {
      float s = 0.f;
#pragma unroll
      for (int c = 0; c < 16; ++c) s = fmaxf(s, fabsf(Tacc[c]));
#pragma unroll
      for (int off = 32; off >= 1; off >>= 1) s = fmaxf(s, __shfl_xor(s, off));
      const float inv = 1.f / (s + EPSF);
      log_norm += logf(s + EPSF);
      float tn[16], tp[16];
#pragma unroll
      for (int c = 0; c < 16; ++c) tn[c] = Tacc[c] * inv;
#pragma unroll
      for (int c = 0; c < 16; ++c) tp[c] = __shfl_xor(tn[c], 32);
#pragma unroll
      for (int k = 0; k < 16; ++k) {
        Tall[k] = hi ? tp[k] : tn[k];
        Tall[16 + k] = hi ? tn[k] : tp[k];
      }
    } else {
      if (lane == 0) out[n] = logf(fmaxf(Tacc[0], 0.f) + EPSF) + log_norm;
    }
    bs += nm * 16384;
  }
}

// ---------------- partition chain: 8 blocks x 256 thr, 32 waves = 16e x 2 j-halves ----------------
extern "C" __global__ void __launch_bounds__(256, 1)
tn_part(const short* __restrict__ As, float* __restrict__ Part, int* __restrict__ cnt,
        float* __restrict__ out) {
  __shared__ __align__(16) float Mlds[32 * 36];
  __shared__ __align__(16) float Cw4[4][32 * 20];   // per-wave C[k][j-slice 16], pad 20
  __shared__ float red[4];

  const int tid = threadIdx.x;
  const int lane = tid & 63;
  const int w = tid >> 6;
  const int i = lane & 31;
  const int hi = lane >> 5;
  const int pw = blockIdx.x * 4 + w;   // 0..31
  const int e = pw & 15;
  const int jh = pw >> 4;              // 0 or 1
  float* Cw = Cw4[w];

  for (int t = tid; t < 32 * 36; t += 256) Mlds[t] = 0.f;
  __syncthreads();
  if (tid == 0) Mlds[0] = 1.f;         // M_init = e0 e0^T
  __syncthreads();

  float log_norm = 0.f;
  int bs = 0, par = 0;
#pragma unroll 1
  for (int site = 0; site < 128; ++site) {
    const int nm = ((site & 7) == 0) ? 16 : 1;
    float Macc[8];
#pragma unroll
    for (int c = 0; c < 8; ++c) Macc[c] = 0.f;

#pragma unroll 1
    for (int m = 0; m < nm; ++m) {
      const int sb = bs + m * 16384;
      // GEMM1: C[k_out=i][j] = sum_k M[i][k] * A[k][e][j], j = jh*16 + 8*hi + c
      float acc[8];
#pragma unroll
      for (int c = 0; c < 8; ++c) acc[c] = 0.f;
#pragma unroll
      for (int k = 0; k < 32; ++k) {
        const s16x8 av = *(const s16x8*)&As[sb + (k * 16 + e) * 32 + jh * 16 + 8 * hi];
        const float mik = Mlds[i * 36 + k];
#pragma unroll
        for (int c = 0; c < 8; ++c) acc[c] = fmaf(mik, bf2f(av[c]), acc[c]);
      }
      {
        float4 o0, o1;
        o0.x = acc[0]; o0.y = acc[1]; o0.z = acc[2]; o0.w = acc[3];
        o1.x = acc[4]; o1.y = acc[5]; o1.z = acc[6]; o1.w = acc[7];
        *(float4*)&Cw[i * 20 + 8 * hi] = o0;
        *(float4*)&Cw[i * 20 + 8 * hi + 4] = o1;
      }
      // GEMM2: Macc[i][j] += sum_k A[k][e][i] * C[k][j]   (wave-private Cw)
#pragma unroll
      for (int k = 0; k < 32; ++k) {
        const float ak = bf2f(As[sb + (k * 16 + e) * 32 + i]);
        const float4 c0 = *(const float4*)&Cw[k * 20 + 8 * hi];
        const float4 c1 = *(const float4*)&Cw[k * 20 + 8 * hi + 4];
        Macc[0] = fmaf(ak, c0.x, Macc[0]); Macc[1] = fmaf(ak, c0.y, Macc[1]);
        Macc[2] = fmaf(ak, c0.z, Macc[2]); Macc[3] = fmaf(ak, c0.w, Macc[3]);
        Macc[4] = fmaf(ak, c1.x, Macc[4]); Macc[5] = fmaf(ak, c1.y, Macc[5]);
        Macc[6] = fmaf(ak, c1.z, Macc[6]); Macc[7] = fmaf(ak, c1.w, Macc[7]);
      }
    }

    // ---- write partial slice to global, inter-block barrier ----
    {
      float* pp = &Part[((par * 2 + jh) * 16 + e) * 512 + i * 16 + 8 * hi];
      float4 o0, o1;
      o0.x = Macc[0]; o0.y = Macc[1]; o0.z = Macc[2]; o0.w = Macc[3];
      o1.x = Macc[4]; o1.y = Macc[5]; o1.z = Macc[6]; o1.w = Macc[7];
      *(float4*)pp = o0;
      *(float4*)(pp + 4) = o1;
    }
    __threadfence();
    __syncthreads();
    if (tid == 0) {
      __hip_atomic_fetch_add(cnt, 1, __ATOMIC_RELEASE, __HIP_MEMORY_SCOPE_AGENT);
      while (__hip_atomic_load(cnt, __ATOMIC_ACQUIRE, __HIP_MEMORY_SCOPE_AGENT) < 8 * (site + 1)) {}
    }
    __syncthreads();

    // ---- every block: merge 16 e-partials, rescale, update Mlds ----
    float mv[4], lmax = 0.f;
#pragma unroll
    for (int q = 0; q < 4; ++q) {
      const int flat = tid * 4 + q, i2 = flat >> 5, j2 = flat & 31;
      float sum = 0.f;
#pragma unroll
      for (int e2 = 0; e2 < 16; ++e2)
        sum += Part[((par * 2 + (j2 >> 4)) * 16 + e2) * 512 + i2 * 16 + (j2 & 15)];
      mv[q] = sum;
      lmax = fmaxf(lmax, fabsf(sum));
    }
#pragma unroll
    for (int off = 32; off >= 1; off >>= 1) lmax = fmaxf(lmax, __shfl_xor(lmax, off));
    if (lane == 0) red[w] = lmax;
    __syncthreads();
    const float s = fmaxf(fmaxf(red[0], red[1]), fmaxf(red[2], red[3]));
    if (site < 127) {
      const float inv = 1.f / (s + EPSF);
      log_norm += logf(s + EPSF);
#pragma unroll
      for (int q = 0; q < 4; ++q) {
        const int flat = tid * 4 + q;
        Mlds[(flat >> 5) * 36 + (flat & 31)] = mv[q] * inv;
      }
    } else {
      if (blockIdx.x == 0 && tid == 0)
        out[1024] = logf(fmaxf(mv[0], 0.f) + EPSF) + log_norm;
    }
    __syncthreads();
    par ^= 1;
    bs += nm * 16384;
  }
}

extern "C" void kernel_launch(void* const* d_in, const int* in_sizes, int n_in,
                              void* d_out, int out_size, void* d_ws, size_t ws_size,
                              hipStream_t stream) {
  (void)in_sizes; (void)n_in; (void)out_size; (void)ws_size;
  const float* x   = (const float*)d_in[0];
  const float* wb  = (const float*)d_in[1];
  const float* wsm = (const float*)d_in[2];
  short* As   = (short*)d_ws;                          // 12,058,624 B
  float* Em   = (float*)((char*)d_ws + 12058624);      //  8,388,608 B
  float* Part = (float*)((char*)d_ws + 20447232);      //    131,072 B (site-parity dbuf)
  int*   cnt  = (int*)((char*)d_ws + 20578304);
  float* out  = (float*)d_out;                         // 1024 logits + log_Z

  hipMemsetAsync(cnt, 0, 64, stream);
  prep_emb_k<<<512, 256, 0, stream>>>(x, Em);
  prep_w_k<<<128, 256, 0, stream>>>(wb, wsm, As);
  tn_samples<<<256, 256, 0, stream>>>(As, Em, out);
  tn_part<<<8, 256, 0, stream>>>(As, Part, cnt, out);
}

// Round 4
// 2625.636 us; speedup vs baseline: 1.9321x; 1.9321x over previous
//
#include <hip/hip_runtime.h>

typedef __attribute__((ext_vector_type(8)))  short  s16x8;
typedef __attribute__((ext_vector_type(8)))  __bf16 bf16x8;
typedef __attribute__((ext_vector_type(16))) float  f32x16;

#define EPSF 1e-36f
#define FENCE() asm volatile("" ::: "memory")

static __device__ __forceinline__ f32x16 MFMA(s16x8 a, s16x8 b, f32x16 c) {
  return __builtin_amdgcn_mfma_f32_32x32x16_bf16(
      __builtin_bit_cast(bf16x8, a), __builtin_bit_cast(bf16x8, b), c, 0, 0, 0);
}

static __device__ __forceinline__ float bf2f(short s) {
  return __builtin_bit_cast(float, ((unsigned)(unsigned short)s) << 16);
}

static __device__ __forceinline__ short f2bf(float f) {
  unsigned u = __builtin_bit_cast(unsigned, f);
  u = (u + 0x7FFFu + ((u >> 16) & 1u)) >> 16;
  return (short)u;
}

// D (f32x16, C/D layout: col=lane&31, row=(reg&3)+8*(reg>>2)+4*(lane>>5)) ->
// bf16 operand fragments (slot t of chunk kk = matrix[16kk+8h+t][c31]) via
// wave-private LDS. FENCE keeps the compiler from hoisting the cross-lane
// ds_reads above the ds_writes; HW DS is in-order per wave.
static __device__ __forceinline__ void redistLDS(float* Ex, const f32x16 d, float sc,
                                                 int c31, int h, s16x8& f0, s16x8& f1) {
  FENCE();
#pragma unroll
  for (int reg = 0; reg < 16; ++reg) {
    int row = (reg & 3) + 8 * (reg >> 2) + 4 * h;
    Ex[row * 33 + c31] = d[reg] * sc;
  }
  FENCE();
  __builtin_amdgcn_sched_barrier(0);
  s16x8 a, b;
#pragma unroll
  for (int t = 0; t < 8; ++t) {
    a[t] = f2bf(Ex[(8 * h + t) * 33 + c31]);
    b[t] = f2bf(Ex[(16 + 8 * h + t) * 33 + c31]);
  }
  FENCE();
  f0 = a; f1 = b;
}

// flat step sig in [0,368): 16 groups of (big site: 16 m-steps, 7 small sites: 1 step)
static __device__ __forceinline__ void decodeStep(int sig, int& site, int& m, int& off) {
  int g = sig / 23, o = sig - g * 23;
  if (o < 16) { site = 8 * g; m = o; off = g * 376832 + o * 16384; }
  else { site = 8 * g + (o - 15); m = 0; off = g * 376832 + 262144 + (o - 16) * 16384; }
}

// ---------------- prep: embedding table Em[site][n][16] (f32) ----------------
extern "C" __global__ void prep_emb_k(const float* __restrict__ x, float* __restrict__ Em) {
  int id = blockIdx.x * 256 + threadIdx.x;   // 128 sites * 1024 samples
  int site = id >> 10, n = id & 1023;
  float x0 = x[(n * 128 + site) * 2 + 0];
  float x1 = x[(n * 128 + site) * 2 + 1];
  const float P5 = 1.57079632679f, P25 = 0.785398163397f, R = 0.70710678118f;
  float u[4] = {sinf(P5 * x0) * R, cosf(P5 * x0) * R, sinf(P25 * x0) * R, cosf(P25 * x0) * R};
  float v[4] = {sinf(P5 * x1) * R, cosf(P5 * x1) * R, sinf(P25 * x1) * R, cosf(P25 * x1) * R};
#pragma unroll
  for (int a = 0; a < 4; ++a) {
    float4 o;
    o.x = u[a] * v[0]; o.y = u[a] * v[1]; o.z = u[a] * v[2]; o.w = u[a] * v[3];
    *(float4*)&Em[id * 16 + a * 4] = o;
  }
}

// ---------------- prep: weights -> bf16, layout As[site-flat][m][r][e][l] ----------------
extern "C" __global__ void prep_w_k(const float* __restrict__ wb, const float* __restrict__ wsm,
                                    short* __restrict__ As) {
  int site = blockIdx.x;
  bool big = (site & 7) == 0;
  int nE = big ? 262144 : 16384;
  int nb = (site + 7) >> 3;
  int bs = nb * 262144 + (site - nb) * 16384;
  int kb = site >> 3;
  int ksm = site - kb - 1;
  for (int i = threadIdx.x; i < nE; i += 256) {
    int l = i & 31, e = (i >> 5) & 15, r = (i >> 9) & 31, m = i >> 14;
    float val = big ? wb[(((kb * 32 + l) * 16 + e) * 16 + m) * 32 + r]
                    : wsm[((ksm * 32 + l) * 16 + e) * 32 + r];
    if (site == 0 && l != 0) val = 0.f;
    if (site == 127 && r != 0) val = 0.f;
    As[bs + i] = f2bf(val);
  }
}

// ---------------- merged main: blocks 0..255 = samples (4/block), block 256 = partition ----------------
extern "C" __global__ void __launch_bounds__(256, 2)
tn_main(const short* __restrict__ As, const float* __restrict__ Em, float* __restrict__ out) {
  __shared__ __align__(16) float ExA[4][1064];   // 32*33 = 1056 (+8 pad), per wave
  const int tid = threadIdx.x;
  const int lane = tid & 63;
  const int w = tid >> 6;
  const int c31 = lane & 31;
  const int h = lane >> 5;
  float* Ex = ExA[w];
  const f32x16 Z = {0.f,0.f,0.f,0.f,0.f,0.f,0.f,0.f,0.f,0.f,0.f,0.f,0.f,0.f,0.f,0.f};

  s16x8 Mf0 = {0,0,0,0,0,0,0,0}, Mf1 = {0,0,0,0,0,0,0,0};
  if (lane == 0) Mf0[0] = (short)0x3F80;   // M_init = e0 e0^T (bf16 1.0)
  f32x16 Macc = Z;
  float log_norm = 0.f;

  if (blockIdx.x < 256) {
    // ============ sample chains: wave = sample, no block barriers ============
    const int n = blockIdx.x * 4 + w;
    float er[16];
#pragma unroll 1
    for (int sig = 0; sig < 368; ++sig) {
      int site, m, off; decodeStep(sig, site, m, off);
      if (m == 0) {
        const float4* ep = (const float4*)&Em[(site * 1024 + n) * 16];
        float4 q0 = ep[0], q1 = ep[1], q2 = ep[2], q3 = ep[3];
        er[0] = q0.x; er[1] = q0.y; er[2] = q0.z; er[3] = q0.w;
        er[4] = q1.x; er[5] = q1.y; er[6] = q1.z; er[7] = q1.w;
        er[8] = q2.x; er[9] = q2.y; er[10] = q2.z; er[11] = q2.w;
        er[12] = q3.x; er[13] = q3.y; er[14] = q3.z; er[15] = q3.w;
      }
      // ---- B-form from global (L2): lane owns col r=c31, rows l in [16h,16h+16) ----
      float acc[16];
#pragma unroll
      for (int c = 0; c < 16; ++c) acc[c] = 0.f;
      {
        const short* rp = As + off + c31 * 512 + h * 16;
#pragma unroll
        for (int e = 0; e < 16; ++e) {
          s16x8 v0 = *(const s16x8*)(rp + e * 32);
          s16x8 v1 = *(const s16x8*)(rp + e * 32 + 8);
          const float ce = er[e];
#pragma unroll
          for (int c = 0; c < 8; ++c) {
            acc[c]     = fmaf(ce, bf2f(v0[c]), acc[c]);
            acc[8 + c] = fmaf(ce, bf2f(v1[c]), acc[8 + c]);
          }
        }
      }
      // ---- cross-lane exchange to MFMA fragments (wave-private LDS, fenced) ----
      FENCE();
#pragma unroll
      for (int c = 0; c < 16; ++c) Ex[(16 * h + c) * 33 + c31] = acc[c];
      FENCE();
      __builtin_amdgcn_sched_barrier(0);
      s16x8 Bf0, Bf1;
#pragma unroll
      for (int t = 0; t < 8; ++t) {
        Bf0[t] = f2bf(Ex[(8 * h + t) * 33 + c31]);
        Bf1[t] = f2bf(Ex[(16 + 8 * h + t) * 33 + c31]);
      }
      FENCE();
      // ---- sandwich: Macc += B^T (M B) ----
      f32x16 D1 = MFMA(Mf0, Bf0, Z);
      D1 = MFMA(Mf1, Bf1, D1);
      s16x8 Cf0, Cf1;
      redistLDS(Ex, D1, 1.f, c31, h, Cf0, Cf1);
      if (m == 0) Macc = Z;
      Macc = MFMA(Bf0, Cf0, Macc);
      Macc = MFMA(Bf1, Cf1, Macc);

      bool lastM = (m == (((site & 7) == 0) ? 15 : 0));
      if (lastM) {
        if (site < 127) {
          float s = fabsf(Macc[0]);
#pragma unroll
          for (int j = 1; j < 16; ++j) s = fmaxf(s, fabsf(Macc[j]));
#pragma unroll
          for (int off2 = 32; off2 >= 1; off2 >>= 1) s = fmaxf(s, __shfl_xor(s, off2));
          float inv = 1.f / (s + EPSF);
          log_norm += logf(s + EPSF);
          redistLDS(Ex, Macc, inv, c31, h, Mf0, Mf1);
        } else {
          if (lane == 0) out[n] = logf(fmaxf(Macc[0], 0.f) + EPSF) + log_norm;
        }
      }
    }
  } else {
    // ============ partition chain (log_Z): 1 block, 4 waves x 4 e each ============
#pragma unroll 1
    for (int sig = 0; sig < 368; ++sig) {
      int site, m, off; decodeStep(sig, site, m, off);
      if (m == 0) Macc = Z;
#pragma unroll
      for (int q = 0; q < 4; ++q) {
        int e = 4 * w + q;
        const short* ap = As + off + (c31 * 16 + e) * 32;
        s16x8 Bf0 = *(const s16x8*)(ap + 8 * h);
        s16x8 Bf1 = *(const s16x8*)(ap + 16 + 8 * h);
        f32x16 D1 = MFMA(Mf0, Bf0, Z);
        D1 = MFMA(Mf1, Bf1, D1);
        s16x8 Cf0, Cf1;
        redistLDS(Ex, D1, 1.f, c31, h, Cf0, Cf1);
        Macc = MFMA(Bf0, Cf0, Macc);
        Macc = MFMA(Bf1, Cf1, Macc);
      }
      bool lastM = (m == (((site & 7) == 0) ? 15 : 0));
      if (lastM) {
        FENCE();
#pragma unroll
        for (int reg = 0; reg < 16; ++reg) {
          int row = (reg & 3) + 8 * (reg >> 2) + 4 * h;
          Ex[row * 33 + c31] = Macc[reg];
        }
        __syncthreads();
        f32x16 tot;
#pragma unroll
        for (int reg = 0; reg < 16; ++reg) {
          int row = (reg & 3) + 8 * (reg >> 2) + 4 * h;
          int idx = row * 33 + c31;
          tot[reg] = ExA[0][idx] + ExA[1][idx] + ExA[2][idx] + ExA[3][idx];
        }
        float s = fabsf(tot[0]);
#pragma unroll
        for (int j = 1; j < 16; ++j) s = fmaxf(s, fabsf(tot[j]));
#pragma unroll
        for (int off2 = 32; off2 >= 1; off2 >>= 1) s = fmaxf(s, __shfl_xor(s, off2));
        __syncthreads();   // all sums read before Ex reuse below
        if (site < 127) {
          float inv = 1.f / (s + EPSF);
          log_norm += logf(s + EPSF);
          redistLDS(Ex, tot, inv, c31, h, Mf0, Mf1);
        } else {
          if (tid == 0) out[1024] = logf(fmaxf(tot[0], 0.f) + EPSF) + log_norm;
        }
      }
    }
  }
}

extern "C" void kernel_launch(void* const* d_in, const int* in_sizes, int n_in,
                              void* d_out, int out_size, void* d_ws, size_t ws_size,
                              hipStream_t stream) {
  (void)in_sizes; (void)n_in; (void)out_size; (void)ws_size;
  const float* x   = (const float*)d_in[0];
  const float* wb  = (const float*)d_in[1];
  const float* wsm = (const float*)d_in[2];
  short* As = (short*)d_ws;                          // 12,058,624 B
  float* Em = (float*)((char*)d_ws + 12058624);      //  8,388,608 B
  float* out = (float*)d_out;                        // 1024 logits + log_Z

  prep_emb_k<<<512, 256, 0, stream>>>(x, Em);
  prep_w_k<<<128, 256, 0, stream>>>(wb, wsm, As);
  tn_main<<<257, 256, 0, stream>>>(As, Em, out);
}

// Round 6
// 1083.675 us; speedup vs baseline: 4.6812x; 2.4229x over previous
//
#include <hip/hip_runtime.h>

typedef __attribute__((ext_vector_type(8)))  short  s16x8;
typedef __attribute__((ext_vector_type(8)))  __bf16 bf16x8;
typedef __attribute__((ext_vector_type(16))) float  f32x16;
typedef __attribute__((ext_vector_type(4)))  unsigned int u32x4;

#define EPSF 1e-36f

static __device__ __forceinline__ f32x16 MFMA(s16x8 a, s16x8 b, f32x16 c) {
  return __builtin_amdgcn_mfma_f32_32x32x16_bf16(
      __builtin_bit_cast(bf16x8, a), __builtin_bit_cast(bf16x8, b), c, 0, 0, 0);
}

static __device__ __forceinline__ short f2bf(float f) {
  unsigned u = __builtin_bit_cast(unsigned, f);
  u = (u + 0x7FFFu + ((u >> 16) & 1u)) >> 16;
  return (short)u;
}

// pack two floats to bf16 pair {lo=a, hi=b} -- pure bit math, unambiguous
static __device__ __forceinline__ unsigned pkf(float a, float b) {
  return (unsigned)(unsigned short)f2bf(a) | ((unsigned)(unsigned short)f2bf(b) << 16);
}

static __device__ __forceinline__ float bf2f(short s) {
  return __builtin_bit_cast(float, ((unsigned)(unsigned short)s) << 16);
}

// D (C/D layout: col=lane&31, row=(reg&3)+8*(reg>>2)+4h) -> two k-chunk bf16
// operand fragments (slot t of chunk kk = matrix[16kk+8h+t][c31]).
// In-register: pack pairs to bf16, half-swap with lane^32.
// h=0 holds rows {0-3,8-11,16-19,24-27}; h=1 holds {4-7,12-15,20-23,28-31}.
static __device__ __forceinline__ void redistR(const f32x16 d, float sc, int h,
                                               s16x8& f0, s16x8& f1) {
  unsigned pk[8];
#pragma unroll
  for (int q = 0; q < 8; ++q) pk[q] = pkf(d[2 * q] * sc, d[2 * q + 1] * sc);
  unsigned s0 = h ? pk[0] : pk[2];
  unsigned s1 = h ? pk[1] : pk[3];
  unsigned s2 = h ? pk[4] : pk[6];
  unsigned s3 = h ? pk[5] : pk[7];
  unsigned r0 = (unsigned)__shfl_xor((int)s0, 32);
  unsigned r1 = (unsigned)__shfl_xor((int)s1, 32);
  unsigned r2 = (unsigned)__shfl_xor((int)s2, 32);
  unsigned r3 = (unsigned)__shfl_xor((int)s3, 32);
  u32x4 a, b;
  a.x = h ? r0 : pk[0]; a.y = h ? r1 : pk[1]; a.z = h ? pk[2] : r0; a.w = h ? pk[3] : r1;
  b.x = h ? r2 : pk[4]; b.y = h ? r3 : pk[5]; b.z = h ? pk[6] : r2; b.w = h ? pk[7] : r3;
  f0 = __builtin_bit_cast(s16x8, a);
  f1 = __builtin_bit_cast(s16x8, b);
}

// flat step sig in [0,368): 16 groups of (big site: 16 m-steps, 7 small sites: 1 step)
static __device__ __forceinline__ void decodeStep(int sig, int& site, int& m, int& off) {
  int g = sig / 23, o = sig - g * 23;
  if (o < 16) { site = 8 * g; m = o; off = g * 376832 + o * 16384; }
  else { site = 8 * g + (o - 15); m = 0; off = g * 376832 + 262144 + (o - 16) * 16384; }
}

// ---------------- prep: embedding table Em[site][n][16] (f32) ----------------
extern "C" __global__ void prep_emb_k(const float* __restrict__ x, float* __restrict__ Em) {
  int id = blockIdx.x * 256 + threadIdx.x;   // 128 sites * 1024 samples
  int site = id >> 10, n = id & 1023;
  float x0 = x[(n * 128 + site) * 2 + 0];
  float x1 = x[(n * 128 + site) * 2 + 1];
  const float P5 = 1.57079632679f, P25 = 0.785398163397f, R = 0.70710678118f;
  float u[4] = {sinf(P5 * x0) * R, cosf(P5 * x0) * R, sinf(P25 * x0) * R, cosf(P25 * x0) * R};
  float v[4] = {sinf(P5 * x1) * R, cosf(P5 * x1) * R, sinf(P25 * x1) * R, cosf(P25 * x1) * R};
#pragma unroll
  for (int a = 0; a < 4; ++a) {
    float4 o;
    o.x = u[a] * v[0]; o.y = u[a] * v[1]; o.z = u[a] * v[2]; o.w = u[a] * v[3];
    *(float4*)&Em[id * 16 + a * 4] = o;
  }
}

// ---------------- prep: weights -> bf16, layout As[site-flat][m][r][e][l] ----------------
extern "C" __global__ void prep_w_k(const float* __restrict__ wb, const float* __restrict__ wsm,
                                    short* __restrict__ As) {
  int site = blockIdx.x;
  bool big = (site & 7) == 0;
  int nE = big ? 262144 : 16384;
  int nb = (site + 7) >> 3;
  int bs = nb * 262144 + (site - nb) * 16384;
  int kb = site >> 3;
  int ksm = site - kb - 1;
  for (int i = threadIdx.x; i < nE; i += 256) {
    int l = i & 31, e = (i >> 5) & 15, r = (i >> 9) & 31, m = i >> 14;
    float val = big ? wb[(((kb * 32 + l) * 16 + e) * 16 + m) * 32 + r]
                    : wsm[((ksm * 32 + l) * 16 + e) * 32 + r];
    if (site == 0 && l != 0) val = 0.f;
    if (site == 127 && r != 0) val = 0.f;
    As[bs + i] = f2bf(val);
  }
}

// ---------------- merged main: blocks 0..255 = samples (4/block), block 256 = partition ----------------
extern "C" __global__ void __launch_bounds__(256, 2)
tn_main(const short* __restrict__ As, const float* __restrict__ Em, float* __restrict__ out) {
  // 2 x 32KB staging double-buffer (sample blocks); partition block aliases for reduce
  __shared__ __align__(16) char smem[65536];
  const int tid = threadIdx.x;
  const int lane = tid & 63;
  const int w = tid >> 6;
  const int c31 = lane & 31;
  const int h = lane >> 5;
  const f32x16 Z = {0.f,0.f,0.f,0.f,0.f,0.f,0.f,0.f,0.f,0.f,0.f,0.f,0.f,0.f,0.f,0.f};

  s16x8 Mf0 = {0,0,0,0,0,0,0,0}, Mf1 = {0,0,0,0,0,0,0,0};
  if (lane == 0) Mf0[0] = (short)0x3F80;   // M_init = e0 e0^T (bf16 1.0)
  f32x16 Macc = Z;
  float log_norm = 0.f;

  if (blockIdx.x < 256) {
    // ============ sample chains: wave = sample, block-shared staged A slice ============
    const int n = blockIdx.x * 4 + w;
    float er[16];

    // prologue: stage slice 0 into buffer 0 (plain loads + swizzled ds_write)
    {
      const short* src = As;   // decodeStep(0) -> off 0
#pragma unroll
      for (int k = 0; k < 8; ++k) {
        s16x8 v = *(const s16x8*)(src + (k * 256 + tid) * 8);
        int G = k * 256 + tid, r = G >> 6, p = G & 63;
        *(s16x8*)(smem + (r * 64 + (p ^ (r & 7))) * 16) = v;
      }
    }
    __syncthreads();

#pragma unroll 1
    for (int sig = 0; sig < 368; ++sig) {
      int site, m, off; decodeStep(sig, site, m, off); (void)off;
      char* cur = smem + ((sig & 1) << 15);
      char* nxt = smem + (((sig + 1) & 1) << 15);

      // ---- T14 issue-early: load next slice into registers (latency hides under compute) ----
      s16x8 pre[8];
      const bool hasNext = (sig + 1 < 368);
      if (hasNext) {
        int st2, m2, off2; decodeStep(sig + 1, st2, m2, off2);
        const short* src = As + off2;
#pragma unroll
        for (int k = 0; k < 8; ++k)
          pre[k] = *(const s16x8*)(src + (k * 256 + tid) * 8);
      }

      if (m == 0) {
        const float4* ep = (const float4*)&Em[(site * 1024 + n) * 16];
        float4 q0 = ep[0], q1 = ep[1], q2 = ep[2], q3 = ep[3];
        er[0] = q0.x; er[1] = q0.y; er[2] = q0.z; er[3] = q0.w;
        er[4] = q1.x; er[5] = q1.y; er[6] = q1.z; er[7] = q1.w;
        er[8] = q2.x; er[9] = q2.y; er[10] = q2.z; er[11] = q2.w;
        er[12] = q3.x; er[13] = q3.y; er[14] = q3.z; er[15] = q3.w;
      }

      // ---- B-form from LDS (swizzled reads): acc[c] = B[l=16h+c][r=c31] ----
      float acc[16];
#pragma unroll
      for (int c = 0; c < 16; ++c) acc[c] = 0.f;
      {
        const char* rowp = cur + c31 * 1024;
        const int sw = (c31 & 7) << 4;
#pragma unroll
        for (int e = 0; e < 16; ++e) {
          s16x8 v0 = *(const s16x8*)(rowp + (((e * 4 + 2 * h + 0) << 4) ^ sw));
          s16x8 v1 = *(const s16x8*)(rowp + (((e * 4 + 2 * h + 1) << 4) ^ sw));
          const float ce = er[e];
#pragma unroll
          for (int c = 0; c < 8; ++c) {
            acc[c]     = fmaf(ce, bf2f(v0[c]), acc[c]);
            acc[8 + c] = fmaf(ce, bf2f(v1[c]), acc[8 + c]);
          }
        }
      }
      // ---- in-register half-swap -> B fragments ----
      s16x8 Bf0, Bf1;
      {
        unsigned o0[4], o1[4];
        o0[0] = pkf(acc[0], acc[1]);   o0[1] = pkf(acc[2], acc[3]);
        o0[2] = pkf(acc[4], acc[5]);   o0[3] = pkf(acc[6], acc[7]);
        o1[0] = pkf(acc[8], acc[9]);   o1[1] = pkf(acc[10], acc[11]);
        o1[2] = pkf(acc[12], acc[13]); o1[3] = pkf(acc[14], acc[15]);
        u32x4 b0, b1;
#pragma unroll
        for (int q = 0; q < 4; ++q) {
          unsigned snd = h ? o0[q] : o1[q];
          unsigned rcv = (unsigned)__shfl_xor((int)snd, 32);
          ((unsigned*)&b0)[q] = h ? rcv : o0[q];
          ((unsigned*)&b1)[q] = h ? o1[q] : rcv;
        }
        Bf0 = __builtin_bit_cast(s16x8, b0);
        Bf1 = __builtin_bit_cast(s16x8, b1);
      }

      // ---- sandwich: Macc += B^T (M B)  (M symmetric) ----
      f32x16 D1 = MFMA(Mf0, Bf0, Z);
      D1 = MFMA(Mf1, Bf1, D1);
      s16x8 Cf0, Cf1;
      redistR(D1, 1.f, h, Cf0, Cf1);
      if (m == 0) Macc = Z;
      Macc = MFMA(Bf0, Cf0, Macc);
      Macc = MFMA(Bf1, Cf1, Macc);

      bool lastM = (m == (((site & 7) == 0) ? 15 : 0));
      if (lastM) {
        if (site < 127) {
          float s = fabsf(Macc[0]);
#pragma unroll
          for (int j = 1; j < 16; ++j) s = fmaxf(s, fabsf(Macc[j]));
#pragma unroll
          for (int off2 = 32; off2 >= 1; off2 >>= 1) s = fmaxf(s, __shfl_xor(s, off2));
          float inv = 1.f / (s + EPSF);
          log_norm += logf(s + EPSF);
          redistR(Macc, inv, h, Mf0, Mf1);
        } else {
          if (lane == 0) out[n] = logf(fmaxf(Macc[0], 0.f) + EPSF) + log_norm;
        }
      }

      // ---- write-late: staged registers -> next buffer (swizzled ds_write) ----
      if (hasNext) {
#pragma unroll
        for (int k = 0; k < 8; ++k) {
          int G = k * 256 + tid, r = G >> 6, p = G & 63;
          *(s16x8*)(nxt + (r * 64 + (p ^ (r & 7))) * 16) = pre[k];
        }
      }
      __syncthreads();   // writes visible; all reads of cur complete before reuse
    }
  } else {
    // ============ partition chain (log_Z): 1 block, 4 waves x 4 e each ============
    float* red = (float*)smem;            // [4 waves][32*33] f32
#pragma unroll 1
    for (int sig = 0; sig < 368; ++sig) {
      int site, m, off; decodeStep(sig, site, m, off);
      if (m == 0) Macc = Z;
      // hoist all 8 fragment loads (independent -> deep in flight)
      s16x8 pa[4], pb[4];
#pragma unroll
      for (int q = 0; q < 4; ++q) {
        int e = 4 * w + q;
        const short* ap = As + off + (c31 * 16 + e) * 32;
        pa[q] = *(const s16x8*)(ap + 8 * h);
        pb[q] = *(const s16x8*)(ap + 16 + 8 * h);
      }
#pragma unroll
      for (int q = 0; q < 4; ++q) {
        f32x16 D1 = MFMA(Mf0, pa[q], Z);
        D1 = MFMA(Mf1, pb[q], D1);
        s16x8 Cf0, Cf1;
        redistR(D1, 1.f, h, Cf0, Cf1);
        Macc = MFMA(pa[q], Cf0, Macc);
        Macc = MFMA(pb[q], Cf1, Macc);
      }
      bool lastM = (m == (((site & 7) == 0) ? 15 : 0));
      if (lastM) {
        float* myr = red + w * 1056;
#pragma unroll
        for (int reg = 0; reg < 16; ++reg) {
          int row = (reg & 3) + 8 * (reg >> 2) + 4 * h;
          myr[row * 33 + c31] = Macc[reg];
        }
        __syncthreads();
        f32x16 tot;
#pragma unroll
        for (int reg = 0; reg < 16; ++reg) {
          int row = (reg & 3) + 8 * (reg >> 2) + 4 * h;
          int idx = row * 33 + c31;
          tot[reg] = red[idx] + red[1056 + idx] + red[2112 + idx] + red[3168 + idx];
        }
        float s = fabsf(tot[0]);
#pragma unroll
        for (int j = 1; j < 16; ++j) s = fmaxf(s, fabsf(tot[j]));
#pragma unroll
        for (int off2 = 32; off2 >= 1; off2 >>= 1) s = fmaxf(s, __shfl_xor(s, off2));
        __syncthreads();   // all reads done before red[] reuse
        if (site < 127) {
          float inv = 1.f / (s + EPSF);
          log_norm += logf(s + EPSF);
          redistR(tot, inv, h, Mf0, Mf1);
        } else {
          if (tid == 0) out[1024] = logf(fmaxf(tot[0], 0.f) + EPSF) + log_norm;
        }
      }
    }
  }
}

extern "C" void kernel_launch(void* const* d_in, const int* in_sizes, int n_in,
                              void* d_out, int out_size, void* d_ws, size_t ws_size,
                              hipStream_t stream) {
  (void)in_sizes; (void)n_in; (void)out_size; (void)ws_size;
  const float* x   = (const float*)d_in[0];
  const float* wb  = (const float*)d_in[1];
  const float* wsm = (const float*)d_in[2];
  short* As = (short*)d_ws;                          // 12,058,624 B
  float* Em = (float*)((char*)d_ws + 12058624);      //  8,388,608 B
  float* out = (float*)d_out;                        // 1024 logits + log_Z

  prep_emb_k<<<512, 256, 0, stream>>>(x, Em);
  prep_w_k<<<128, 256, 0, stream>>>(wb, wsm, As);
  tn_main<<<257, 256, 0, stream>>>(As, Em, out);
}